// Round 15
// baseline (3012.362 us; speedup 1.0000x reference)
//
#include <hip/hip_runtime.h>

// 2-layer tanh RNN, T=512, B=64, IC=HC=1024, fp32 in/out.
// Fully-fused persistent kernel, 4 groups of 64 WGs x 512 threads (grid 256):
//   G3 (wg 192..255): pre1[t] = x[t]*Wi1^T + b1  (pipelined producer, leads)
//   G0 (wg 0..63):    h1[s]   = tanh(pre1[s] + h1[s-1]*Wh1^T)        s=0..511
//   G1 (wg 64..127):  pre2[s-1] = h1[s-1]*Wi2^T + b2                 s=1..512
//   G2 (wg 128..191): h2[s-2] = tanh(pre2[s-2] + h2[s-3]*Wh2^T)      s=2..513
// Cross-WG data: sc0/sc1 write-through stores + sc0/sc1 coherent loads
// (x is read-only input -> ordinary cacheable loads for G3).
// Per-store-wave flags; 16-flag lane-parallel A-gates; frag-parallel epilogue.
// Split-bf16 (hi+lo, drop lo*lo) MFMA 16x16x32, fp32 accumulate.
// pre1 lives in seqO slot t: G3 write < G0 read (stage t) < G2 overwrite (t+2).

#define T_STEPS 512
#define HCC     1024
#define BH      65536
#define NWG     256

typedef __attribute__((ext_vector_type(8))) short  bf16x8;
typedef __attribute__((ext_vector_type(4))) float  f32x4;

// ws layout: WF 16 MiB | h1F 4 slabs | h2F 4 slabs | pre2 4 slots | flags
#define WF_SHORTS   8388608u
#define SLAB_SHORTS 131072u
#define OFF_H1F     WF_SHORTS
#define OFF_H2F     (OFF_H1F + 4u*SLAB_SHORTS)
#define OFF_PRE2_BYTES ((size_t)(OFF_H2F + 4u*SLAB_SHORTS) * 2u)   /* 18,874,368 */
#define PRE2_FLOATS 65536u
#define FLG_BYTE_OFF (OFF_PRE2_BYTES + 4u*(size_t)PRE2_FLOATS*4u)  /* 19,922,944 */
#define FLG_UINTS   (4u*64u*4u*4u)           /* [g][sub][wp], 16B-strided */

__device__ __forceinline__ unsigned fidx(unsigned g, unsigned i, unsigned wp) {
    return ((g * 64u + i) * 4u + wp) * 4u;
}

// ---- raw 16B loads/stores; VMEM ordering handled manually ----
__device__ __forceinline__ void gload_b128_cc(bf16x8& d, const unsigned short* p) {
    asm volatile("global_load_dwordx4 %0, %1, off sc0 sc1" : "=v"(d) : "v"(p));
}
__device__ __forceinline__ void gload_f128_cc(f32x4& d, const float* p) {
    asm volatile("global_load_dwordx4 %0, %1, off sc0 sc1" : "=v"(d) : "v"(p));
}
__device__ __forceinline__ void gload_f128_nc(f32x4& d, const float* p) {
    asm volatile("global_load_dwordx4 %0, %1, off" : "=v"(d) : "v"(p));
}
__device__ __forceinline__ void gstore_b128_cc(bf16x8 v, unsigned short* p) {
    asm volatile("global_store_dwordx4 %0, %1, off sc0 sc1" :: "v"(p), "v"(v) : "memory");
}
__device__ __forceinline__ void gstore_f128_cc(f32x4 v, float* p) {
    asm volatile("global_store_dwordx4 %0, %1, off sc0 sc1" :: "v"(p), "v"(v) : "memory");
}
__device__ __forceinline__ void vm_drain()  { asm volatile("s_waitcnt vmcnt(0)"  ::: "memory"); }
__device__ __forceinline__ void vm_wait8()  { asm volatile("s_waitcnt vmcnt(8)"  ::: "memory"); }
#define SBAR() __builtin_amdgcn_sched_barrier(0)

__device__ __forceinline__ unsigned short bf16_rne_bits(float f) {
    unsigned u = __builtin_bit_cast(unsigned, f);
    unsigned r = u + 0x7fffu + ((u >> 16) & 1u);
    return (unsigned short)(r >> 16);
}
__device__ __forceinline__ void split1(float f, unsigned short& hi, unsigned short& lo) {
    unsigned u = __builtin_bit_cast(unsigned, f);
    unsigned r = (u + 0x7fffu + ((u >> 16) & 1u)) & 0xffff0000u;
    hi = (unsigned short)(r >> 16);
    float res = f - __builtin_bit_cast(float, r);
    lo = bf16_rne_bits(res);
}
__device__ __forceinline__ void split8(const float* f, bf16x8& H, bf16x8& L) {
#pragma unroll
    for (int e = 0; e < 8; ++e) {
        unsigned short hi, lo; split1(f[e], hi, lo);
        H[e] = (short)hi; L[e] = (short)lo;
    }
}
__device__ __forceinline__ float tanh_fast(float v) {
    float e = __expf(2.0f * v);
    return 1.0f - 2.0f * __builtin_amdgcn_rcpf(e + 1.0f);
}

__global__ __launch_bounds__(256) void zero_cnt_kernel(unsigned* cnt, unsigned n) {
    unsigned i = blockIdx.x * 256u + threadIdx.x;
    if (i < n) cnt[i] = 0u;
}

// ---------------- weight split to fragment-major ----------------
// WF[mat][prec][c16][ks][lane*8+e]; mat: 0=Wi1 1=Wh1 2=Wi2 3=Wh2
__global__ __launch_bounds__(256) void wsplit_kernel(
    const float* __restrict__ Wi, const float* __restrict__ Wh,
    unsigned short* __restrict__ WF)
{
    unsigned id  = blockIdx.x * 256u + threadIdx.x;   // < 524288
    unsigned kc  = id & 127u;
    unsigned row = (id >> 7) & 1023u;
    unsigned m   = id >> 17;                           // 0..3

    const float* src = ((m & 1u) ? Wh : Wi) + (size_t)(m >> 1) * HCC * HCC
                     + (size_t)row * HCC + kc * 8u;
    float f[8];
    *(f32x4*)&f[0] = *(const f32x4*)&src[0];
    *(f32x4*)&f[4] = *(const f32x4*)&src[4];
    bf16x8 H, L; split8(f, H, L);

    unsigned c16 = row >> 4, ks = kc >> 2;
    unsigned lane = (row & 15u) + 16u * (kc & 3u);
    size_t bh_ = (((size_t)(m * 2u + 0u) * 64u + c16) * 32u + ks) * 512u + lane * 8u;
    size_t bl_ = (((size_t)(m * 2u + 1u) * 64u + c16) * 32u + ks) * 512u + lane * 8u;
    *(bf16x8*)&WF[bh_] = H;
    *(bf16x8*)&WF[bl_] = L;
}

// ---------------- persistent 4-group pipeline ----------------
__global__ __launch_bounds__(512, 1) void rnn_persist(
    const float* __restrict__ xin,
    const float* __restrict__ bi, const float* __restrict__ bh,
    const unsigned short* __restrict__ WF,
    unsigned short* __restrict__ h1F, unsigned short* __restrict__ h2F,
    float* __restrict__ pre2F, unsigned* __restrict__ flg,
    float* __restrict__ seqO, float* __restrict__ hsO)
{
    __shared__ short WlS[65536];       // 128 KiB weights (G3 uses first 64 KiB)
    __shared__ float redS[7168];       // 28 KiB: slot(f,wi)=f*7+wi; quadrant f at f*7

    const unsigned wg  = blockIdx.x;
    const unsigned grp = wg >> 6;                // 0,1,2,3
    const unsigned sub = wg & 63u;
    const unsigned rh  = sub >> 5, ct = sub & 31u;
    const unsigned tid = threadIdx.x;
    const unsigned w   = tid >> 6, lane = tid & 63u;  // w = K-eighth; w<4 = frag-wave

    const unsigned mat = (grp == 3u) ? 0u : (grp + 1u);  // G3:Wi1, G0:Wh1, G1:Wi2, G2:Wh2
#pragma unroll
    for (unsigned prec = 0; prec < 2; ++prec)
#pragma unroll
        for (unsigned c16l = 0; c16l < 2; ++c16l) {
            const unsigned short* sp = WF + (((size_t)(mat * 2u + prec) * 64u + (ct * 2u + c16l)) * 32u) * 512u;
            short* dp = &WlS[(prec * 2u + c16l) * 16384u];
            for (unsigned o = tid * 8u; o < 16384u; o += 4096u)
                *(bf16x8*)&dp[o] = *(const bf16x8*)&sp[o];
        }
    __syncthreads();   // WlS staged cross-wave

    float bsel = 0.f;
    if ((grp == 1u || grp == 3u) && w < 4u) {
        unsigned c = (grp == 1u ? HCC : 0u) + ct * 32u + (w & 1u) * 16u + (lane & 15u);
        bsel = bi[c] + bh[c];
    }

    const int s0_ = (grp == 1u) ? 1 : (grp == 2u) ? 2 : 0;
    const int s1_ = s0_ + 511;

#define POLL16(G, TGT) do {                                                           \
        const unsigned* fp_ = flg + fidx((G), rh * 32u + w * 4u + ((lane >> 2) & 3u), \
                                         lane & 3u);                                  \
        while (!__all((int)(__hip_atomic_load(fp_, __ATOMIC_RELAXED,                  \
                                              __HIP_MEMORY_SCOPE_AGENT) >= (unsigned)(TGT)))) \
            __builtin_amdgcn_s_sleep(1);                                              \
    } while (0)
#define POLLW0(G, TGT) do {                                                           \
        const unsigned* fp_ = flg + fidx((G), lane, 0u);                              \
        while (!__all((int)(__hip_atomic_load(fp_, __ATOMIC_RELAXED,                  \
                                              __HIP_MEMORY_SCOPE_AGENT) >= (unsigned)(TGT)))) \
            __builtin_amdgcn_s_sleep(1);                                              \
    } while (0)
#define POLLG1(TGT) do {                                                              \
        const unsigned* fp_ = flg + fidx(1u, sub, lane & 3u);                         \
        while (!__all((int)(__hip_atomic_load(fp_, __ATOMIC_RELAXED,                  \
                                              __HIP_MEMORY_SCOPE_AGENT) >= (unsigned)(TGT)))) \
            __builtin_amdgcn_s_sleep(1);                                              \
    } while (0)
#define POLLP(G, IDX, WP, TGT) do {                                                   \
        const unsigned* fp_ = flg + fidx((G), (IDX), (WP));                           \
        while (__hip_atomic_load(fp_, __ATOMIC_RELAXED,                               \
                                 __HIP_MEMORY_SCOPE_AGENT) < (unsigned)(TGT))         \
            __builtin_amdgcn_s_sleep(1);                                              \
    } while (0)

    for (int s = s0_; s <= s1_; ++s) {
        const bool do_h = (grp == 0u) ? (s > 0) : (grp == 1u) ? true
                        : (grp == 2u) ? (s > 2) : false;

        // ---- acc-init issue + A-gate polls ----
        f32x4 ldq = {0, 0, 0, 0};
        if (grp == 0u) {
            if (w < 4u) {
                POLLP(3u, sub, w, (unsigned)s + 1u);   // G3 (same sub) finished pre1[s]
                const float* pp = seqO + (((size_t)s * 2u + rh) * 32u + ct) * 1024u;
                gload_f128_cc(ldq, pp + w * 256u + lane * 4u);
            }
            if (s >= 1) POLL16(0u, s);
        } else if (grp == 1u) {
            POLL16(0u, s);
        } else if (grp == 2u) {
            if (w < 4u) {
                POLLG1(s);   // G1 frag flags >= s  =>  pre2[s-2] complete
                const float* pp = pre2F + (size_t)((s - 2) & 3) * PRE2_FLOATS
                                + ((size_t)rh * 32u + ct) * 1024u;
                gload_f128_cc(ldq, pp + w * 256u + lane * 4u);
            }
            if (s >= 3) POLL16(2u, s);
        }
        // grp==3: no polls (free-running producer)

        // ---- A operands ----
        bool do_mm = do_h;
        bf16x8 Ah0[4], Ah1[4], Al0[4], Al1[4];
        if (do_h) {
            const unsigned aslot = (grp == 2u) ? ((unsigned)(s - 3) & 3u)
                                               : ((unsigned)(s - 1) & 3u);
            const unsigned short* Aslab = (grp <= 1u ? h1F : h2F)
                                        + (size_t)aslot * SLAB_SHORTS;
            const unsigned b00 = ((rh * 2u + 0u) * 2u + 0u) * 16384u;
            const unsigned b01 = ((rh * 2u + 0u) * 2u + 1u) * 16384u;
            const unsigned b10 = ((rh * 2u + 1u) * 2u + 0u) * 16384u;
            const unsigned b11 = ((rh * 2u + 1u) * 2u + 1u) * 16384u;
#pragma unroll
            for (unsigned i = 0; i < 4; ++i) {
                const unsigned ao = (w * 4u + i) * 512u + lane * 8u;
                gload_b128_cc(Ah0[i], Aslab + b00 + ao);
                gload_b128_cc(Ah1[i], Aslab + b01 + ao);
            }
#pragma unroll
            for (unsigned i = 0; i < 4; ++i) {
                const unsigned ao = (w * 4u + i) * 512u + lane * 8u;
                gload_b128_cc(Al0[i], Aslab + b10 + ao);
                gload_b128_cc(Al1[i], Aslab + b11 + ao);
            }
        } else if (grp == 3u) {
            // x[t] slice, cacheable loads in A-frag pattern, split in-register
            const float* xt = xin + (size_t)s * BH;
#pragma unroll
            for (unsigned r16 = 0; r16 < 2; ++r16) {
                f32x4 xv[8];
#pragma unroll
                for (unsigned i = 0; i < 4; ++i) {
                    const unsigned row = rh * 32u + r16 * 16u + (lane & 15u);
                    const unsigned k0  = (w * 4u + i) * 32u + (lane >> 4) * 8u;
                    gload_f128_nc(xv[i * 2u],      xt + (size_t)row * 1024u + k0);
                    gload_f128_nc(xv[i * 2u + 1u], xt + (size_t)row * 1024u + k0 + 4u);
                }
                vm_drain(); SBAR();
#pragma unroll
                for (unsigned i = 0; i < 4; ++i) {
                    float fb[8];
                    *(f32x4*)&fb[0] = xv[i * 2u];
                    *(f32x4*)&fb[4] = xv[i * 2u + 1u];
                    if (r16 == 0u) split8(fb, Ah0[i], Al0[i]);
                    else           split8(fb, Ah1[i], Al1[i]);
                }
            }
            do_mm = true;
        }

        f32x4 a00 = {0,0,0,0}, a01 = {0,0,0,0}, a10 = {0,0,0,0}, a11 = {0,0,0,0};
        if (do_mm) {
            // phase 1: Ah x {Bh, Bl} (do_h: while Al streams)
            if (do_h) vm_wait8();
            SBAR();
#pragma unroll
            for (unsigned i = 0; i < 4; ++i) {
                const unsigned ao = (w * 4u + i) * 512u + lane * 8u;
                bf16x8 bh0 = *(const bf16x8*)&WlS[ao];
                bf16x8 bh1 = *(const bf16x8*)&WlS[16384u + ao];
                bf16x8 bl0 = *(const bf16x8*)&WlS[32768u + ao];
                bf16x8 bl1 = *(const bf16x8*)&WlS[49152u + ao];
                a00 = __builtin_amdgcn_mfma_f32_16x16x32_bf16(Ah0[i], bh0, a00, 0, 0, 0);
                a01 = __builtin_amdgcn_mfma_f32_16x16x32_bf16(Ah0[i], bh1, a01, 0, 0, 0);
                a10 = __builtin_amdgcn_mfma_f32_16x16x32_bf16(Ah1[i], bh0, a10, 0, 0, 0);
                a11 = __builtin_amdgcn_mfma_f32_16x16x32_bf16(Ah1[i], bh1, a11, 0, 0, 0);
                a00 = __builtin_amdgcn_mfma_f32_16x16x32_bf16(Ah0[i], bl0, a00, 0, 0, 0);
                a01 = __builtin_amdgcn_mfma_f32_16x16x32_bf16(Ah0[i], bl1, a01, 0, 0, 0);
                a10 = __builtin_amdgcn_mfma_f32_16x16x32_bf16(Ah1[i], bl0, a10, 0, 0, 0);
                a11 = __builtin_amdgcn_mfma_f32_16x16x32_bf16(Ah1[i], bl1, a11, 0, 0, 0);
            }
            // phase 2: Al x Bh
            if (do_h) vm_drain();
            SBAR();
#pragma unroll
            for (unsigned i = 0; i < 4; ++i) {
                const unsigned ao = (w * 4u + i) * 512u + lane * 8u;
                bf16x8 bh0 = *(const bf16x8*)&WlS[ao];
                bf16x8 bh1 = *(const bf16x8*)&WlS[16384u + ao];
                a00 = __builtin_amdgcn_mfma_f32_16x16x32_bf16(Al0[i], bh0, a00, 0, 0, 0);
                a01 = __builtin_amdgcn_mfma_f32_16x16x32_bf16(Al0[i], bh1, a01, 0, 0, 0);
                a10 = __builtin_amdgcn_mfma_f32_16x16x32_bf16(Al1[i], bh0, a10, 0, 0, 0);
                a11 = __builtin_amdgcn_mfma_f32_16x16x32_bf16(Al1[i], bh1, a11, 0, 0, 0);
            }
        } else {
            vm_drain(); SBAR();
        }

        // ---- anti-dep polls (gate only the post-barrier stores) ----
        if (w == 1u) {
            if (grp == 0u && s >= 4) POLLW0(1u, s - 2); // G1 done reading h1[s-4]
            if (grp == 1u && s >= 5) POLLW0(2u, s - 2); // G2 done reading pre2[s-5]
        }
        if (w == 2u) {
            if (grp == 0u && s >= 4) POLLW0(0u, s - 2); // G0 done reading h1[s-4]
            if (grp == 2u && s >= 6) POLLW0(2u, s - 2); // G2 done reading h2[s-6]
        }

        // ---- partials to redS: wave w writes frags f != w (w<4) / all (w>=4) ----
        {
            f32x4 av[4] = {a00, a01, a10, a11};
#pragma unroll
            for (unsigned f = 0; f < 4; ++f) {
                const bool skip = (w < 4u) && (f == w);
                const unsigned wi = w - ((w > f) ? 1u : 0u);
                if (!skip)
                    *(f32x4*)&redS[(f * 7u + wi) * 256u + lane * 4u] = av[f];
            }
        }
        __syncthreads();                                   // barrier 1

        // ---- frag-parallel reduce + epilogue (waves 0..3) ----
        if (w < 4u) {
            f32x4 acc = (w == 0u) ? a00 : (w == 1u) ? a01 : (w == 2u) ? a10 : a11;
#pragma unroll
            for (unsigned b = 0; b < 7; ++b)
                acc += *(const f32x4*)&redS[(w * 7u + b) * 256u + lane * 4u];
            if (grp == 1u) {
                acc += (f32x4){bsel, bsel, bsel, bsel};
                float* pp = pre2F + (size_t)((s - 1) & 3) * PRE2_FLOATS
                          + ((size_t)rh * 32u + ct) * 1024u;
                gstore_f128_cc(acc, pp + w * 256u + lane * 4u);
                vm_drain();
                if (lane == 0u)
                    __hip_atomic_store(flg + fidx(1u, sub, w), (unsigned)s + 1u,
                                       __ATOMIC_RELAXED, __HIP_MEMORY_SCOPE_AGENT);
            } else if (grp == 3u) {
                acc += (f32x4){bsel, bsel, bsel, bsel};
                float* pp = seqO + (((size_t)s * 2u + rh) * 32u + ct) * 1024u;
                gstore_f128_cc(acc, pp + w * 256u + lane * 4u);
                vm_drain();
                if (lane == 0u)
                    __hip_atomic_store(flg + fidx(3u, sub, w), (unsigned)s + 1u,
                                       __ATOMIC_RELAXED, __HIP_MEMORY_SCOPE_AGENT);
            } else {
                acc += ldq;
                // tanh -> quadrant w (16x16) parked at slot w*7 (own slots read above)
                const unsigned qb = w * 1792u;
                const unsigned rb = (lane >> 4) * 4u;
#pragma unroll
                for (unsigned rr = 0; rr < 4; ++rr)
                    redS[qb + (rb + rr) * 16u + (lane & 15u)] = tanh_fast(acc[rr]);
            }
        }
        if (grp == 0u || grp == 2u) {
            __syncthreads();                               // barrier 2: quadrants ready
            if (w < 4u) {
                const unsigned r16l = w >> 1, prec = w & 1u;
                const unsigned c0 = (lane >> 4) * 8u;
                const unsigned q  = r16l * 2u + (c0 >> 4);
                const unsigned qa = q * 1792u + (lane & 15u) * 16u + (c0 & 15u);
                float f[8];
                *(f32x4*)&f[0] = *(const f32x4*)&redS[qa];
                *(f32x4*)&f[4] = *(const f32x4*)&redS[qa + 4u];
                bf16x8 H, L; split8(f, H, L);
                unsigned short* hdst = (grp == 0u ? h1F : h2F)
                    + (size_t)((unsigned)(grp == 0u ? s : s - 2) & 3u) * SLAB_SHORTS;
                gstore_b128_cc(prec ? L : H,
                    hdst + ((rh * 2u + prec) * 2u + r16l) * 16384u + ct * 512u + lane * 8u);
                vm_drain();
                if (lane == 0u)
                    __hip_atomic_store(flg + fidx(grp, sub, w), (unsigned)s + 1u,
                                       __ATOMIC_RELAXED, __HIP_MEMORY_SCOPE_AGENT);
            }
            if (grp == 2u) {
                const int t2 = s - 2;
#pragma unroll
                for (unsigned pass = 0; pass < 2; ++pass) {
                    const unsigned r = w * 4u + pass * 2u + (lane >> 5);
                    const unsigned c = lane & 31u;
                    const float v = redS[((r >> 4) * 2u + (c >> 4)) * 1792u
                                         + (r & 15u) * 16u + (c & 15u)];
                    seqO[((size_t)t2 * 64u + rh * 32u + r) * 1024u + ct * 32u + c] = v;
                    if (s == 513) hsO[BH + (size_t)(rh * 32u + r) * 1024u + ct * 32u + c] = v;
                }
            }
            if (grp == 0u && s == 511) {
#pragma unroll
                for (unsigned pass = 0; pass < 2; ++pass) {
                    const unsigned r = w * 4u + pass * 2u + (lane >> 5);
                    const unsigned c = lane & 31u;
                    hsO[(size_t)(rh * 32u + r) * 1024u + ct * 32u + c]
                        = redS[((r >> 4) * 2u + (c >> 4)) * 1792u
                               + (r & 15u) * 16u + (c & 15u)];
                }
            }
        }
        // ---- stage-end barrier: redS/quadrant WAR protection ----
        __syncthreads();
    }
    vm_drain();
#undef POLL16
#undef POLLW0
#undef POLLG1
#undef POLLP
}

extern "C" void kernel_launch(void* const* d_in, const int* in_sizes, int n_in,
                              void* d_out, int out_size, void* d_ws, size_t ws_size,
                              hipStream_t stream) {
    const float* x  = (const float*)d_in[0];
    const float* Wi = (const float*)d_in[1];
    const float* bi = (const float*)d_in[2];
    const float* Wh = (const float*)d_in[3];
    const float* bh = (const float*)d_in[4];

    float* seqO = (float*)d_out;
    float* hsO  = seqO + (size_t)T_STEPS * BH;

    unsigned short* wsS = (unsigned short*)d_ws;
    unsigned short* WF  = wsS;
    unsigned short* h1F = wsS + OFF_H1F;
    unsigned short* h2F = wsS + OFF_H2F;
    float* pre2F = (float*)((char*)d_ws + OFF_PRE2_BYTES);
    unsigned* flg = (unsigned*)((char*)d_ws + FLG_BYTE_OFF);

    zero_cnt_kernel<<<(FLG_UINTS + 255u) / 256u, 256, 0, stream>>>(flg, FLG_UINTS);
    wsplit_kernel<<<2048, 256, 0, stream>>>(Wi, Wh, WF);
    rnn_persist<<<NWG, 512, 0, stream>>>(x, bi, bh, WF, h1F, h2F, pre2F, flg, seqO, hsO);
}

// Round 17
// 2601.667 us; speedup vs baseline: 1.1579x; 1.1579x over previous
//
#include <hip/hip_runtime.h>

// 2-layer tanh RNN, T=512, B=64, IC=HC=1024, fp32 in/out.
// pre1 = x*Wi1+b precomputed (parallel MFMA GEMM, frag-major into d_out;
// 2 timesteps per block -> W frags loaded once per ks for both).
// Persistent kernel (ROUND-14 structure, known good): 3 groups of 64 WGs x
// 512 threads (waves = K-eighths); sc0/sc1 write-through stores + coherent
// loads; per-store-wave flags; 16-flag lane-parallel A-gates; frag-parallel
// epilogue (wave j<4 owns output frag j).
//   G0 (wg 0..63):    h1[s]   = tanh(pre1[s] + h1[s-1]*Wh1^T)        s=0..511
//   G1 (wg 64..127):  pre2[s-1] = h1[s-1]*Wi2^T + b2                 s=1..512
//   G2 (wg 128..191): h2[s-2] = tanh(pre2[s-2] + h2[s-3]*Wh2^T)      s=2..513
// Split-bf16 (hi+lo, drop lo*lo) MFMA 16x16x32, fp32 accumulate.

#define T_STEPS 512
#define HCC     1024
#define BH      65536
#define NWG     192

typedef __attribute__((ext_vector_type(8))) short  bf16x8;
typedef __attribute__((ext_vector_type(4))) float  f32x4;

// ws layout: WF 16 MiB | h1F 4 slabs | h2F 4 slabs | pre2 4 slots | flags
#define WF_SHORTS   8388608u
#define SLAB_SHORTS 131072u
#define OFF_H1F     WF_SHORTS
#define OFF_H2F     (OFF_H1F + 4u*SLAB_SHORTS)
#define OFF_PRE2_BYTES ((size_t)(OFF_H2F + 4u*SLAB_SHORTS) * 2u)   /* 18,874,368 */
#define PRE2_FLOATS 65536u
#define FLG_BYTE_OFF (OFF_PRE2_BYTES + 4u*(size_t)PRE2_FLOATS*4u)  /* 19,922,944 */
#define FLG_UINTS   (3u*64u*4u*4u)           /* [g][sub][wp], 16B-strided */

__device__ __forceinline__ unsigned fidx(unsigned g, unsigned i, unsigned wp) {
    return ((g * 64u + i) * 4u + wp) * 4u;
}

// ---- raw 16B loads/stores; VMEM ordering handled manually ----
__device__ __forceinline__ void gload_b128_cc(bf16x8& d, const unsigned short* p) {
    asm volatile("global_load_dwordx4 %0, %1, off sc0 sc1" : "=v"(d) : "v"(p));
}
__device__ __forceinline__ void gload_f128_cc(f32x4& d, const float* p) {
    asm volatile("global_load_dwordx4 %0, %1, off sc0 sc1" : "=v"(d) : "v"(p));
}
__device__ __forceinline__ void gload_f128_nc(f32x4& d, const float* p) {
    asm volatile("global_load_dwordx4 %0, %1, off" : "=v"(d) : "v"(p));
}
__device__ __forceinline__ void gstore_b128_cc(bf16x8 v, unsigned short* p) {
    asm volatile("global_store_dwordx4 %0, %1, off sc0 sc1" :: "v"(p), "v"(v) : "memory");
}
__device__ __forceinline__ void gstore_f128_cc(f32x4 v, float* p) {
    asm volatile("global_store_dwordx4 %0, %1, off sc0 sc1" :: "v"(p), "v"(v) : "memory");
}
__device__ __forceinline__ void vm_drain()  { asm volatile("s_waitcnt vmcnt(0)"  ::: "memory"); }
__device__ __forceinline__ void vm_wait8()  { asm volatile("s_waitcnt vmcnt(8)"  ::: "memory"); }
#define SBAR() __builtin_amdgcn_sched_barrier(0)

__device__ __forceinline__ unsigned short bf16_rne_bits(float f) {
    unsigned u = __builtin_bit_cast(unsigned, f);
    unsigned r = u + 0x7fffu + ((u >> 16) & 1u);
    return (unsigned short)(r >> 16);
}
__device__ __forceinline__ void split1(float f, unsigned short& hi, unsigned short& lo) {
    unsigned u = __builtin_bit_cast(unsigned, f);
    unsigned r = (u + 0x7fffu + ((u >> 16) & 1u)) & 0xffff0000u;
    hi = (unsigned short)(r >> 16);
    float res = f - __builtin_bit_cast(float, r);
    lo = bf16_rne_bits(res);
}
__device__ __forceinline__ void split8(const float* f, bf16x8& H, bf16x8& L) {
#pragma unroll
    for (int e = 0; e < 8; ++e) {
        unsigned short hi, lo; split1(f[e], hi, lo);
        H[e] = (short)hi; L[e] = (short)lo;
    }
}
__device__ __forceinline__ float tanh_fast(float v) {
    float e = __expf(2.0f * v);
    return 1.0f - 2.0f * __builtin_amdgcn_rcpf(e + 1.0f);
}

__global__ __launch_bounds__(256) void zero_cnt_kernel(unsigned* cnt, unsigned n) {
    unsigned i = blockIdx.x * 256u + threadIdx.x;
    if (i < n) cnt[i] = 0u;
}

// ---------------- weight split to fragment-major ----------------
// WF[mat][prec][c16][ks][lane*8+e]; mat: 0=Wi1 1=Wh1 2=Wi2 3=Wh2
__global__ __launch_bounds__(256) void wsplit_kernel(
    const float* __restrict__ Wi, const float* __restrict__ Wh,
    unsigned short* __restrict__ WF)
{
    unsigned id  = blockIdx.x * 256u + threadIdx.x;   // < 524288
    unsigned kc  = id & 127u;
    unsigned row = (id >> 7) & 1023u;
    unsigned m   = id >> 17;                           // 0..3

    const float* src = ((m & 1u) ? Wh : Wi) + (size_t)(m >> 1) * HCC * HCC
                     + (size_t)row * HCC + kc * 8u;
    float f[8];
    *(f32x4*)&f[0] = *(const f32x4*)&src[0];
    *(f32x4*)&f[4] = *(const f32x4*)&src[4];
    bf16x8 H, L; split8(f, H, L);

    unsigned c16 = row >> 4, ks = kc >> 2;
    unsigned lane = (row & 15u) + 16u * (kc & 3u);
    size_t bh_ = (((size_t)(m * 2u + 0u) * 64u + c16) * 32u + ks) * 512u + lane * 8u;
    size_t bl_ = (((size_t)(m * 2u + 1u) * 64u + c16) * 32u + ks) * 512u + lane * 8u;
    *(bf16x8*)&WF[bh_] = H;
    *(bf16x8*)&WF[bl_] = L;
}

// ---------------- pre1 = x*Wi1^T + (bi1+bh1), frag-major into d_out -------
// 2 timesteps per block: W frags loaded once per ks, applied to both x tiles.
__global__ __launch_bounds__(256) void pre1_gemm(
    const float* __restrict__ x, const float* __restrict__ bi, const float* __restrict__ bh,
    const unsigned short* __restrict__ WF, float* __restrict__ preO)
{
    __shared__ float xs[2][64 * 36];
    const unsigned t0 = (blockIdx.x >> 3) * 2u, cg = blockIdx.x & 7u;
    const unsigned tid = threadIdx.x, w = tid >> 6, lane = tid & 63u;
    const unsigned ct32 = cg * 4u + w;

    float b0 = bi[ct32 * 32u + (lane & 15u)]        + bh[ct32 * 32u + (lane & 15u)];
    float b1 = bi[ct32 * 32u + 16u + (lane & 15u)]  + bh[ct32 * 32u + 16u + (lane & 15u)];
    f32x4 acc[2][4][2];
#pragma unroll
    for (unsigned tt = 0; tt < 2; ++tt)
#pragma unroll
        for (unsigned rt = 0; rt < 4; ++rt) {
            acc[tt][rt][0] = (f32x4){b0, b0, b0, b0};
            acc[tt][rt][1] = (f32x4){b1, b1, b1, b1};
        }

    for (unsigned ks = 0; ks < 32; ++ks) {
        {
            unsigned row = tid >> 2, c8 = (tid & 3u) * 8u;
#pragma unroll
            for (unsigned tt = 0; tt < 2; ++tt) {
                const float* sp = x + (size_t)(t0 + tt) * BH + (size_t)row * HCC + ks * 32u + c8;
                *(f32x4*)&xs[tt][row * 36u + c8]      = *(const f32x4*)&sp[0];
                *(f32x4*)&xs[tt][row * 36u + c8 + 4u] = *(const f32x4*)&sp[4];
            }
        }
        __syncthreads();
        bf16x8 bhv[2], blv[2];
#pragma unroll
        for (unsigned c16 = 0; c16 < 2; ++c16) {
            size_t base = (((size_t)(ct32 * 2u + c16)) * 32u + ks) * 512u + lane * 8u;
            bhv[c16] = *(const bf16x8*)&WF[base];
            blv[c16] = *(const bf16x8*)&WF[base + (size_t)64u * 32u * 512u];
        }
#pragma unroll
        for (unsigned tt = 0; tt < 2; ++tt)
#pragma unroll
            for (unsigned rt = 0; rt < 4; ++rt) {
                unsigned row = rt * 16u + (lane & 15u);
                unsigned k0 = (lane >> 4) * 8u;
                float f[8];
                *(f32x4*)&f[0] = *(const f32x4*)&xs[tt][row * 36u + k0];
                *(f32x4*)&f[4] = *(const f32x4*)&xs[tt][row * 36u + k0 + 4u];
                bf16x8 ah, al; split8(f, ah, al);
#pragma unroll
                for (unsigned c16 = 0; c16 < 2; ++c16) {
                    acc[tt][rt][c16] = __builtin_amdgcn_mfma_f32_16x16x32_bf16(ah, bhv[c16], acc[tt][rt][c16], 0, 0, 0);
                    acc[tt][rt][c16] = __builtin_amdgcn_mfma_f32_16x16x32_bf16(al, bhv[c16], acc[tt][rt][c16], 0, 0, 0);
                    acc[tt][rt][c16] = __builtin_amdgcn_mfma_f32_16x16x32_bf16(ah, blv[c16], acc[tt][rt][c16], 0, 0, 0);
                }
            }
        __syncthreads();
    }
#pragma unroll
    for (unsigned tt = 0; tt < 2; ++tt)
#pragma unroll
        for (unsigned rt = 0; rt < 4; ++rt)
#pragma unroll
            for (unsigned c16 = 0; c16 < 2; ++c16) {
                unsigned rh = rt >> 1, fi = (rt & 1u) * 2u + c16;
                size_t off = ((((size_t)(t0 + tt) * 2u + rh) * 32u + ct32) * 4u + fi) * 256u + lane * 4u;
                *(f32x4*)&preO[off] = acc[tt][rt][c16];
            }
}

// ---------------- persistent 3-group pipeline (round 14, verbatim) ----------------
__global__ __launch_bounds__(512, 1) void rnn_persist(
    const float* __restrict__ bi, const float* __restrict__ bh,
    const unsigned short* __restrict__ WF,
    unsigned short* __restrict__ h1F, unsigned short* __restrict__ h2F,
    float* __restrict__ pre2F, unsigned* __restrict__ flg,
    float* __restrict__ seqO, float* __restrict__ hsO)
{
    __shared__ short WlS[65536];       // 128 KiB weights (hi+lo, 32 cols)
    __shared__ float redS[7168];       // 28 KiB: slot(f,wi)=f*7+wi; quadrant f at f*7

    const unsigned wg  = blockIdx.x;
    const unsigned grp = wg >> 6;                // 0,1,2
    const unsigned sub = wg & 63u;
    const unsigned rh  = sub >> 5, ct = sub & 31u;
    const unsigned tid = threadIdx.x;
    const unsigned w   = tid >> 6, lane = tid & 63u;  // w = K-eighth; w<4 = frag-wave

    const unsigned mat = grp + 1u;               // Wh1/Wi2/Wh2
#pragma unroll
    for (unsigned prec = 0; prec < 2; ++prec)
#pragma unroll
        for (unsigned c16l = 0; c16l < 2; ++c16l) {
            const unsigned short* sp = WF + (((size_t)(mat * 2u + prec) * 64u + (ct * 2u + c16l)) * 32u) * 512u;
            short* dp = &WlS[(prec * 2u + c16l) * 16384u];
            for (unsigned o = tid * 8u; o < 16384u; o += 4096u)
                *(bf16x8*)&dp[o] = *(const bf16x8*)&sp[o];
        }
    __syncthreads();   // WlS staged cross-wave

    float bsel = 0.f;
    if (grp == 1u && w < 4u) {
        unsigned c = HCC + ct * 32u + (w & 1u) * 16u + (lane & 15u);
        bsel = bi[c] + bh[c];
    }

    const int s0_ = (grp == 0u) ? 0 : (grp == 1u) ? 1 : 2;
    const int s1_ = s0_ + 511;

#define POLL16(G, TGT) do {                                                           \
        const unsigned* fp_ = flg + fidx((G), rh * 32u + w * 4u + ((lane >> 2) & 3u), \
                                         lane & 3u);                                  \
        while (!__all((int)(__hip_atomic_load(fp_, __ATOMIC_RELAXED,                  \
                                              __HIP_MEMORY_SCOPE_AGENT) >= (unsigned)(TGT)))) \
            __builtin_amdgcn_s_sleep(1);                                              \
    } while (0)
#define POLLW0(G, TGT) do {                                                           \
        const unsigned* fp_ = flg + fidx((G), lane, 0u);                              \
        while (!__all((int)(__hip_atomic_load(fp_, __ATOMIC_RELAXED,                  \
                                              __HIP_MEMORY_SCOPE_AGENT) >= (unsigned)(TGT)))) \
            __builtin_amdgcn_s_sleep(1);                                              \
    } while (0)
#define POLLG1(TGT) do {                                                              \
        const unsigned* fp_ = flg + fidx(1u, sub, lane & 3u);                         \
        while (!__all((int)(__hip_atomic_load(fp_, __ATOMIC_RELAXED,                  \
                                              __HIP_MEMORY_SCOPE_AGENT) >= (unsigned)(TGT)))) \
            __builtin_amdgcn_s_sleep(1);                                              \
    } while (0)

    for (int s = s0_; s <= s1_; ++s) {
        const bool do_h   = (grp == 0u) ? (s > 0) : (grp == 1u) ? true : (s > 2);

        // ---- acc-init issue + A-gate polls ----
        f32x4 ldq = {0, 0, 0, 0};
        if (grp == 0u) {
            if (w < 4u) {   // pre1[s] stable until G2 stage s+2 (>= G0 flag s+1)
                const float* pp = seqO + (((size_t)s * 2u + rh) * 32u + ct) * 1024u;
                gload_f128_nc(ldq, pp + w * 256u + lane * 4u);
            }
            if (s >= 1) POLL16(0u, s);
        } else if (grp == 1u) {
            POLL16(0u, s);
        } else {
            if (w < 4u) {
                POLLG1(s);   // G1 frag flags >= s  =>  pre2[s-2] complete
                const float* pp = pre2F + (size_t)((s - 2) & 3) * PRE2_FLOATS
                                + ((size_t)rh * 32u + ct) * 1024u;
                gload_f128_cc(ldq, pp + w * 256u + lane * 4u);
            }
            if (s >= 3) POLL16(2u, s);
        }

        // ---- A loads: Ah (8) then Al (8) ----
        bf16x8 Ah0[4], Ah1[4], Al0[4], Al1[4];
        if (do_h) {
            const unsigned aslot = (grp == 2u) ? ((unsigned)(s - 3) & 3u)
                                               : ((unsigned)(s - 1) & 3u);
            const unsigned short* Aslab = (grp <= 1u ? h1F : h2F)
                                        + (size_t)aslot * SLAB_SHORTS;
            const unsigned b00 = ((rh * 2u + 0u) * 2u + 0u) * 16384u;
            const unsigned b01 = ((rh * 2u + 0u) * 2u + 1u) * 16384u;
            const unsigned b10 = ((rh * 2u + 1u) * 2u + 0u) * 16384u;
            const unsigned b11 = ((rh * 2u + 1u) * 2u + 1u) * 16384u;
#pragma unroll
            for (unsigned i = 0; i < 4; ++i) {
                const unsigned ao = (w * 4u + i) * 512u + lane * 8u;
                gload_b128_cc(Ah0[i], Aslab + b00 + ao);
                gload_b128_cc(Ah1[i], Aslab + b01 + ao);
            }
#pragma unroll
            for (unsigned i = 0; i < 4; ++i) {
                const unsigned ao = (w * 4u + i) * 512u + lane * 8u;
                gload_b128_cc(Al0[i], Aslab + b10 + ao);
                gload_b128_cc(Al1[i], Aslab + b11 + ao);
            }
        }

        f32x4 a00 = {0,0,0,0}, a01 = {0,0,0,0}, a10 = {0,0,0,0}, a11 = {0,0,0,0};
        if (do_h) {
            // phase 1: Ah x {Bh, Bl} while Al streams
            vm_wait8(); SBAR();
#pragma unroll
            for (unsigned i = 0; i < 4; ++i) {
                const unsigned ao = (w * 4u + i) * 512u + lane * 8u;
                bf16x8 bh0 = *(const bf16x8*)&WlS[ao];
                bf16x8 bh1 = *(const bf16x8*)&WlS[16384u + ao];
                bf16x8 bl0 = *(const bf16x8*)&WlS[32768u + ao];
                bf16x8 bl1 = *(const bf16x8*)&WlS[49152u + ao];
                a00 = __builtin_amdgcn_mfma_f32_16x16x32_bf16(Ah0[i], bh0, a00, 0, 0, 0);
                a01 = __builtin_amdgcn_mfma_f32_16x16x32_bf16(Ah0[i], bh1, a01, 0, 0, 0);
                a10 = __builtin_amdgcn_mfma_f32_16x16x32_bf16(Ah1[i], bh0, a10, 0, 0, 0);
                a11 = __builtin_amdgcn_mfma_f32_16x16x32_bf16(Ah1[i], bh1, a11, 0, 0, 0);
                a00 = __builtin_amdgcn_mfma_f32_16x16x32_bf16(Ah0[i], bl0, a00, 0, 0, 0);
                a01 = __builtin_amdgcn_mfma_f32_16x16x32_bf16(Ah0[i], bl1, a01, 0, 0, 0);
                a10 = __builtin_amdgcn_mfma_f32_16x16x32_bf16(Ah1[i], bl0, a10, 0, 0, 0);
                a11 = __builtin_amdgcn_mfma_f32_16x16x32_bf16(Ah1[i], bl1, a11, 0, 0, 0);
            }
            // phase 2: Al x Bh
            vm_drain(); SBAR();
#pragma unroll
            for (unsigned i = 0; i < 4; ++i) {
                const unsigned ao = (w * 4u + i) * 512u + lane * 8u;
                bf16x8 bh0 = *(const bf16x8*)&WlS[ao];
                bf16x8 bh1 = *(const bf16x8*)&WlS[16384u + ao];
                a00 = __builtin_amdgcn_mfma_f32_16x16x32_bf16(Al0[i], bh0, a00, 0, 0, 0);
                a01 = __builtin_amdgcn_mfma_f32_16x16x32_bf16(Al0[i], bh1, a01, 0, 0, 0);
                a10 = __builtin_amdgcn_mfma_f32_16x16x32_bf16(Al1[i], bh0, a10, 0, 0, 0);
                a11 = __builtin_amdgcn_mfma_f32_16x16x32_bf16(Al1[i], bh1, a11, 0, 0, 0);
            }
        } else {
            vm_drain(); SBAR();
        }

        // ---- anti-dep polls (gate only the post-barrier-2 stores) ----
        if (w == 1u) {
            if (grp == 0u && s >= 4) POLLW0(1u, s - 2); // G1 done reading h1[s-4]
            if (grp == 1u && s >= 5) POLLW0(2u, s - 2); // G2 done reading pre2[s-5]
        }
        if (w == 2u) {
            if (grp == 0u && s >= 4) POLLW0(0u, s - 2); // G0 done reading h1[s-4]
            if (grp == 2u && s >= 6) POLLW0(2u, s - 2); // G2 done reading h2[s-6]
        }

        // ---- partials to redS: wave w writes frags f != w (w<4) / all (w>=4) ----
        {
            f32x4 av[4] = {a00, a01, a10, a11};
#pragma unroll
            for (unsigned f = 0; f < 4; ++f) {
                const bool skip = (w < 4u) && (f == w);
                const unsigned wi = w - ((w > f) ? 1u : 0u);
                if (!skip)
                    *(f32x4*)&redS[(f * 7u + wi) * 256u + lane * 4u] = av[f];
            }
        }
        __syncthreads();                                   // barrier 1

        // ---- frag-parallel reduce + epilogue (waves 0..3) ----
        if (w < 4u) {
            f32x4 acc = (w == 0u) ? a00 : (w == 1u) ? a01 : (w == 2u) ? a10 : a11;
#pragma unroll
            for (unsigned b = 0; b < 7; ++b)
                acc += *(const f32x4*)&redS[(w * 7u + b) * 256u + lane * 4u];
            if (grp == 1u) {
                acc += (f32x4){bsel, bsel, bsel, bsel};
                float* pp = pre2F + (size_t)((s - 1) & 3) * PRE2_FLOATS
                          + ((size_t)rh * 32u + ct) * 1024u;
                gstore_f128_cc(acc, pp + w * 256u + lane * 4u);
                vm_drain();
                if (lane == 0u)
                    __hip_atomic_store(flg + fidx(1u, sub, w), (unsigned)s + 1u,
                                       __ATOMIC_RELAXED, __HIP_MEMORY_SCOPE_AGENT);
            } else {
                acc += ldq;
                // tanh -> quadrant w (16x16) parked at slot w*7 (own slots read above)
                const unsigned qb = w * 1792u;
                const unsigned rb = (lane >> 4) * 4u;
#pragma unroll
                for (unsigned rr = 0; rr < 4; ++rr)
                    redS[qb + (rb + rr) * 16u + (lane & 15u)] = tanh_fast(acc[rr]);
            }
        }
        if (grp != 1u) {
            __syncthreads();                               // barrier 2: quadrants ready
            // h-slab store (waves 0..3): block (prec=w&1, r16l=w>>1)
            if (w < 4u) {
                const unsigned r16l = w >> 1, prec = w & 1u;
                const unsigned c0 = (lane >> 4) * 8u;
                const unsigned q  = r16l * 2u + (c0 >> 4);
                const unsigned qa = q * 1792u + (lane & 15u) * 16u + (c0 & 15u);
                float f[8];
                *(f32x4*)&f[0] = *(const f32x4*)&redS[qa];
                *(f32x4*)&f[4] = *(const f32x4*)&redS[qa + 4u];
                bf16x8 H, L; split8(f, H, L);
                unsigned short* hdst = (grp == 0u ? h1F : h2F)
                    + (size_t)((unsigned)(grp == 0u ? s : s - 2) & 3u) * SLAB_SHORTS;
                gstore_b128_cc(prec ? L : H,
                    hdst + ((rh * 2u + prec) * 2u + r16l) * 16384u + ct * 512u + lane * 8u);
                vm_drain();    // stale seqO stores long retired; waits only h-store
                if (lane == 0u)
                    __hip_atomic_store(flg + fidx(grp, sub, w), (unsigned)s + 1u,
                                       __ATOMIC_RELAXED, __HIP_MEMORY_SCOPE_AGENT);
            }
            // seqO / hsO outputs from quadrants (off the flag path)
            if (grp == 2u) {
                const int t2 = s - 2;
#pragma unroll
                for (unsigned pass = 0; pass < 2; ++pass) {
                    const unsigned r = w * 4u + pass * 2u + (lane >> 5);
                    const unsigned c = lane & 31u;
                    const float v = redS[((r >> 4) * 2u + (c >> 4)) * 1792u
                                         + (r & 15u) * 16u + (c & 15u)];
                    seqO[((size_t)t2 * 64u + rh * 32u + r) * 1024u + ct * 32u + c] = v;
                    if (s == 513) hsO[BH + (size_t)(rh * 32u + r) * 1024u + ct * 32u + c] = v;
                }
            }
            if (grp == 0u && s == 511) {
#pragma unroll
                for (unsigned pass = 0; pass < 2; ++pass) {
                    const unsigned r = w * 4u + pass * 2u + (lane >> 5);
                    const unsigned c = lane & 31u;
                    hsO[(size_t)(rh * 32u + r) * 1024u + ct * 32u + c]
                        = redS[((r >> 4) * 2u + (c >> 4)) * 1792u
                               + (r & 15u) * 16u + (c & 15u)];
                }
            }
        }
        // ---- stage-end barrier: redS/quadrant WAR protection ----
        __syncthreads();
    }
    vm_drain();   // retire straggler seqO stores
#undef POLL16
#undef POLLW0
#undef POLLG1
}

extern "C" void kernel_launch(void* const* d_in, const int* in_sizes, int n_in,
                              void* d_out, int out_size, void* d_ws, size_t ws_size,
                              hipStream_t stream) {
    const float* x  = (const float*)d_in[0];
    const float* Wi = (const float*)d_in[1];
    const float* bi = (const float*)d_in[2];
    const float* Wh = (const float*)d_in[3];
    const float* bh = (const float*)d_in[4];

    float* seqO = (float*)d_out;
    float* hsO  = seqO + (size_t)T_STEPS * BH;

    unsigned short* wsS = (unsigned short*)d_ws;
    unsigned short* WF  = wsS;
    unsigned short* h1F = wsS + OFF_H1F;
    unsigned short* h2F = wsS + OFF_H2F;
    float* pre2F = (float*)((char*)d_ws + OFF_PRE2_BYTES);
    unsigned* flg = (unsigned*)((char*)d_ws + FLG_BYTE_OFF);

    zero_cnt_kernel<<<(FLG_UINTS + 255u) / 256u, 256, 0, stream>>>(flg, FLG_UINTS);
    wsplit_kernel<<<2048, 256, 0, stream>>>(Wi, Wh, WF);
    pre1_gemm<<<2048, 256, 0, stream>>>(x, bi, bh, WF, seqO);
    rnn_persist<<<NWG, 512, 0, stream>>>(bi, bh, WF, h1F, h2F, pre2F, flg, seqO, hsO);
}